// Round 8
// baseline (85.030 us; speedup 1.0000x reference)
//
#include <hip/hip_runtime.h>
#include <math.h>

typedef float f32x16 __attribute__((ext_vector_type(16)));
typedef __bf16 bf16x8 __attribute__((ext_vector_type(8)));

constexpr int DEG = 64;
constexpr int KC  = 32;
constexpr int D   = 64;
constexpr int NPB = 8;    // nodes per block (1-wave pipeline)
constexpr float EPS = 1.1920929e-05f;  // 100 * f32 eps

// LDS layout: row-major [64 rows][8 chunks of 16B], chunk c of row r at slot
// (c ^ (r&7)) -> ushort idx = row*64 + slot*8. Staged via global_load_lds with
// pre-permuted SOURCE chunk sc=(l&7)^(l>>3), linear dest (both-sides rule).
__device__ __forceinline__ int yidx(int row, int c) {
    return (row << 6) + (((c ^ (row & 7)) & 7) << 3);
}

// ---------------- prep: x(f32) -> xhi/xlo(bf16, row-major) + row norms ----------------
__global__ __launch_bounds__(256)
void rgc_prep(const float* __restrict__ x,
              unsigned short* __restrict__ xhi,
              unsigned short* __restrict__ xlo,
              float* __restrict__ xnrm, int nrows) {
    const int id  = blockIdx.x * 256 + threadIdx.x;
    const int row = id >> 3;
    const int c   = id & 7;
    if (row >= nrows) return;
    const float* src = x + ((size_t)row << 6) + (c << 3);
    const float4 v0 = *reinterpret_cast<const float4*>(src);
    const float4 v1 = *reinterpret_cast<const float4*>(src + 4);
    const float fv[8] = {v0.x, v0.y, v0.z, v0.w, v1.x, v1.y, v1.z, v1.w};
    bf16x8 h, e;
    float s = 0.f;
    #pragma unroll
    for (int j = 0; j < 8; ++j) {
        const float f = fv[j];
        s += f * f;
        const __bf16 hb = (__bf16)f;   // RNE
        h[j] = hb;
        e[j] = (__bf16)(f - (float)hb);
    }
    s += __shfl_xor(s, 1); s += __shfl_xor(s, 2); s += __shfl_xor(s, 4);
    if (c == 0) xnrm[row] = s;
    const size_t o = ((size_t)row << 6) + (c << 3);
    *reinterpret_cast<bf16x8*>(xhi + o) = h;
    *reinterpret_cast<bf16x8*>(xlo + o) = e;
}

// ---------------- pipelined main: 1 wave/block, NPB nodes, no barriers ----------------
__global__ __launch_bounds__(64)
void rgc_pipe(const unsigned short* __restrict__ xhi,
              const unsigned short* __restrict__ xlo,
              const float* __restrict__ xnrm,
              const int*   __restrict__ nbr,
              float*       __restrict__ out) {
    __shared__ __align__(16) unsigned short yhi[2][4096];  // 16 KB
    __shared__ __align__(16) unsigned short ylo[2][4096];  // 16 KB

    const int l  = threadIdx.x;   // 0..63
    const long n0 = (long)blockIdx.x * NPB;

    // ---- prologue: all global->reg loads (keeps loop vmcnt counting exact) ----
    int   my[NPB];
    float nrv[NPB];
    #pragma unroll
    for (int i = 0; i < NPB; ++i) my[i] = nbr[(n0 + i) * 64 + l];
    #pragma unroll
    for (int i = 0; i < NPB; ++i) nrv[i] = xnrm[my[i]];

    const int sc = (l & 7) ^ (l >> 3);   // source chunk -> lands at slot l&7

    auto STAGE = [&](int p, int i) {
        #pragma unroll
        for (int j = 0; j < 8; ++j) {
            const int g = __shfl(my[i], 8 * j + (l >> 3));
            const size_t so = ((size_t)g << 6) + (sc << 3);
            __builtin_amdgcn_global_load_lds(
                (const __attribute__((address_space(1))) unsigned int*)(xhi + so),
                (__attribute__((address_space(3))) unsigned int*)(&yhi[p][j << 9]),
                16, 0, 0);
            __builtin_amdgcn_global_load_lds(
                (const __attribute__((address_space(1))) unsigned int*)(xlo + so),
                (__attribute__((address_space(3))) unsigned int*)(&ylo[p][j << 9]),
                16, 0, 0);
        }
    };

    STAGE(0, 0);

    const int frow = l & 31;
    const int kh   = l >> 5;

    #pragma unroll
    for (int i = 0; i < NPB; ++i) {
        const int p = i & 1;
        if (i + 1 < NPB) {
            STAGE(p ^ 1, i + 1);
            asm volatile("s_waitcnt vmcnt(16)" ::: "memory");  // stage(i) done
        } else {
            asm volatile("s_waitcnt vmcnt(0)" ::: "memory");
        }
        __builtin_amdgcn_sched_barrier(0);
        // single wave: wave-synchronous, no s_barrier needed anywhere

        // ---- fragments: D = Xm · Xk^T; k = lane dim (l&31), m = reg dim ----
        bf16x8 bh[4], bl[4], ah2[4], al2[4];
        #pragma unroll
        for (int s = 0; s < 4; ++s) {
            const int c = 2 * s + kh;
            bh[s]  = *reinterpret_cast<const bf16x8*>(&yhi[p][yidx(frow, c)]);
            bl[s]  = *reinterpret_cast<const bf16x8*>(&ylo[p][yidx(frow, c)]);
            ah2[s] = *reinterpret_cast<const bf16x8*>(&yhi[p][yidx(32 + frow, c)]);
            al2[s] = *reinterpret_cast<const bf16x8*>(&ylo[p][yidx(32 + frow, c)]);
        }

        f32x16 acc0 = {}, acc1 = {};
        #pragma unroll
        for (int s = 0; s < 4; ++s) {
            acc0 = __builtin_amdgcn_mfma_f32_32x32x16_bf16(bh[s],  bh[s], acc0, 0, 0, 0);
            acc1 = __builtin_amdgcn_mfma_f32_32x32x16_bf16(ah2[s], bh[s], acc1, 0, 0, 0);
        }
        #pragma unroll
        for (int s = 0; s < 4; ++s) {
            acc0 = __builtin_amdgcn_mfma_f32_32x32x16_bf16(bh[s],  bl[s], acc0, 0, 0, 0);
            acc1 = __builtin_amdgcn_mfma_f32_32x32x16_bf16(ah2[s], bl[s], acc1, 0, 0, 0);
        }
        #pragma unroll
        for (int s = 0; s < 4; ++s) {
            acc0 = __builtin_amdgcn_mfma_f32_32x32x16_bf16(bl[s],  bh[s], acc0, 0, 0, 0);
            acc1 = __builtin_amdgcn_mfma_f32_32x32x16_bf16(al2[s], bh[s], acc1, 0, 0, 0);
        }

        // ---- sq -> l2 -> dist (reduce over all 64 m in-register + 1 shfl) ----
        const float nr = nrv[i];
        const float nk = __shfl(nr, frow);
        float s = 0.f;
        #pragma unroll
        for (int r = 0; r < 16; ++r) {
            const int   m  = (r & 3) + 8 * (r >> 2) + 4 * kh;
            const float nm = __shfl(nr, m);
            const float sq = __builtin_fmaf(-2.0f, acc0[r], nm + nk);
            s += __builtin_amdgcn_sqrtf(__builtin_fabsf(sq) + EPS);
        }
        #pragma unroll
        for (int r = 0; r < 16; ++r) {
            const int   m  = 32 + (r & 3) + 8 * (r >> 2) + 4 * kh;
            const float nm = __shfl(nr, m);
            const float sq = __builtin_fmaf(-2.0f, acc1[r], nm + nk);
            s += __builtin_amdgcn_sqrtf(__builtin_fabsf(sq) + EPS);
        }
        s += __shfl_xor(s, 32);   // full dist_k at lanes k and k+32

        // ---- softmax over 32 candidates (in-wave, replicated across halves) ----
        float dmin = s;
        #pragma unroll
        for (int m = 1; m <= 16; m <<= 1) dmin = fminf(dmin, __shfl_xor(dmin, m));
        const float ez = __expf(dmin - s);
        float Z = ez;
        #pragma unroll
        for (int m = 1; m <= 16; m <<= 1) Z += __shfl_xor(Z, m);
        const float ezs = ez * (64.0f / Z);   // lane k holds w_k (row_sum = DEG)

        // ---- output: lane l -> d-pair (2*(l&31), +1), k-half = l>>5 ----
        const int d0 = (l & 31) << 1;
        float oe = 0.f, oo = 0.f;
        #pragma unroll
        for (int kk = 0; kk < 16; ++kk) {
            const int k  = ((l >> 5) << 4) + kk;
            const float wk = __shfl(ezs, k);
            const int idx = (k << 6) + ((((d0 >> 3) ^ (k & 7)) & 7) << 3) + (d0 & 7);
            const unsigned uh = *reinterpret_cast<const unsigned*>(&yhi[p][idx]);
            const unsigned ul = *reinterpret_cast<const unsigned*>(&ylo[p][idx]);
            const float fe = __uint_as_float(uh << 16) + __uint_as_float(ul << 16);
            const float fo = __uint_as_float(uh & 0xffff0000u) + __uint_as_float(ul & 0xffff0000u);
            oe = __builtin_fmaf(wk, fe, oe);
            oo = __builtin_fmaf(wk, fo, oo);
        }
        oe += __shfl_xor(oe, 32);
        oo += __shfl_xor(oo, 32);
        if (l < 32) {
            float2 v = make_float2(oe, oo);
            *reinterpret_cast<float2*>(out + ((size_t)(n0 + i) << 6) + (l << 1)) = v;
        }
    }
}

// ---------------- fallback (no workspace): R4 path ----------------
__device__ __forceinline__ int yidx_cm(int row, int chunk) {  // old chunk-major
    return (chunk << 9) + ((row ^ chunk) << 3);
}

__global__ __launch_bounds__(128, 4)
void rgc_fallback(const float* __restrict__ x,
                  const int*   __restrict__ nbr,
                  float*       __restrict__ out) {
    __shared__ __align__(16) unsigned short yhi[4096];
    __shared__ __align__(16) unsigned short ylo[4096];
    __shared__ float nrm[64];
    __shared__ float wsh[KC];
    __shared__ float pdist[64];
    __shared__ float obuf[64];

    const int n = blockIdx.x;
    const int t = threadIdx.x;
    const int w = t >> 6;
    const int l = t & 63;

    const int srow = t >> 3;
    const int sc   = t & 7;
    int gidx[4];
    #pragma unroll
    for (int it = 0; it < 4; ++it)
        gidx[it] = nbr[(n << 6) + it * 16 + srow];

    #pragma unroll
    for (int it = 0; it < 4; ++it) {
        const int row = it * 16 + srow;
        const float* src = x + ((size_t)gidx[it] << 6) + (sc << 3);
        const float4 v0 = *reinterpret_cast<const float4*>(src);
        const float4 v1 = *reinterpret_cast<const float4*>(src + 4);
        const float fv[8] = {v0.x, v0.y, v0.z, v0.w, v1.x, v1.y, v1.z, v1.w};
        float s = 0.f;
        bf16x8 h, e;
        #pragma unroll
        for (int j = 0; j < 8; ++j) {
            const float f = fv[j];
            s += f * f;
            const __bf16 hb = (__bf16)f;
            h[j] = hb;
            e[j] = (__bf16)(f - (float)hb);
        }
        s += __shfl_xor(s, 1); s += __shfl_xor(s, 2); s += __shfl_xor(s, 4);
        if (sc == 0) nrm[row] = s;
        const int base = yidx_cm(row, sc);
        *reinterpret_cast<bf16x8*>(&yhi[base]) = h;
        *reinterpret_cast<bf16x8*>(&ylo[base]) = e;
    }
    __syncthreads();

    const int frow = l & 31;
    const int kh   = l >> 5;
    bf16x8 amh[4], aml[4], bkh[4], bkl[4];
    #pragma unroll
    for (int s = 0; s < 4; ++s) {
        const int c  = 2 * s + kh;
        const int kb = yidx_cm(frow, c);
        bkh[s] = *reinterpret_cast<bf16x8*>(&yhi[kb]);
        bkl[s] = *reinterpret_cast<bf16x8*>(&ylo[kb]);
    }
    if (w == 0) {
        #pragma unroll
        for (int s = 0; s < 4; ++s) { amh[s] = bkh[s]; aml[s] = bkl[s]; }
    } else {
        #pragma unroll
        for (int s = 0; s < 4; ++s) {
            const int c  = 2 * s + kh;
            const int mb = yidx_cm(32 + frow, c);
            amh[s] = *reinterpret_cast<bf16x8*>(&yhi[mb]);
            aml[s] = *reinterpret_cast<bf16x8*>(&ylo[mb]);
        }
    }

    f32x16 acc = {};
    #pragma unroll
    for (int s = 0; s < 4; ++s)
        acc = __builtin_amdgcn_mfma_f32_32x32x16_bf16(amh[s], bkh[s], acc, 0, 0, 0);
    #pragma unroll
    for (int s = 0; s < 4; ++s)
        acc = __builtin_amdgcn_mfma_f32_32x32x16_bf16(amh[s], bkl[s], acc, 0, 0, 0);
    #pragma unroll
    for (int s = 0; s < 4; ++s)
        acc = __builtin_amdgcn_mfma_f32_32x32x16_bf16(aml[s], bkh[s], acc, 0, 0, 0);

    const float nk  = nrm[frow];
    const int   mb0 = w * 32 + 4 * kh;
    float s = 0.f;
    #pragma unroll
    for (int r = 0; r < 16; ++r) {
        const float nm = nrm[mb0 + (r & 3) + 8 * (r >> 2)];
        const float sq = __builtin_fmaf(-2.0f, acc[r], nm + nk);
        s += __builtin_amdgcn_sqrtf(__builtin_fabsf(sq) + EPS);
    }
    s += __shfl_xor(s, 32);
    if (l < 32) pdist[w * 32 + l] = s;
    __syncthreads();

    const float dsum = pdist[frow] + pdist[32 + frow];
    float dmin = dsum;
    #pragma unroll
    for (int m = 1; m <= 16; m <<= 1) dmin = fminf(dmin, __shfl_xor(dmin, m));
    const float ez = __expf(dmin - dsum);
    float Z = ez;
    #pragma unroll
    for (int m = 1; m <= 16; m <<= 1) Z += __shfl_xor(Z, m);
    if (t < 32) wsh[frow] = ez * (64.0f / Z);
    __syncthreads();

    const int oc = l >> 3;
    const int ow = l & 7;
    float o = 0.f;
    #pragma unroll
    for (int kk = 0; kk < 16; ++kk) {
        const int kx = w * 16 + kk;
        const int bi = yidx_cm(kx, oc) + ow;
        const float f = __uint_as_float((unsigned)yhi[bi] << 16)
                      + __uint_as_float((unsigned)ylo[bi] << 16);
        o += wsh[kx] * f;
    }
    if (w == 1) obuf[l] = o;
    __syncthreads();
    if (w == 0) out[(size_t)n * D + l] = o + obuf[l];
}

extern "C" void kernel_launch(void* const* d_in, const int* in_sizes, int n_in,
                              void* d_out, int out_size, void* d_ws, size_t ws_size,
                              hipStream_t stream) {
    const float* x   = (const float*)d_in[0];
    const int*   nbr = (const int*)d_in[1];
    float*       out = (float*)d_out;
    const int n_nodes = in_sizes[0] / D;   // 20000
    const size_t need = (size_t)n_nodes * D * 2 * sizeof(unsigned short)
                      + (size_t)n_nodes * sizeof(float);
    if (d_ws != nullptr && ws_size >= need && (n_nodes % NPB) == 0) {
        unsigned short* xhi  = (unsigned short*)d_ws;
        unsigned short* xlo  = xhi + (size_t)n_nodes * D;
        float*          xnrm = (float*)(xlo + (size_t)n_nodes * D);
        const int tasks = n_nodes * 8;
        rgc_prep<<<(tasks + 255) / 256, 256, 0, stream>>>(x, xhi, xlo, xnrm, n_nodes);
        rgc_pipe<<<n_nodes / NPB, 64, 0, stream>>>(xhi, xlo, xnrm, nbr, out);
    } else {
        rgc_fallback<<<n_nodes, 128, 0, stream>>>(x, nbr, out);
    }
}

// Round 9
// 47.960 us; speedup vs baseline: 1.7729x; 1.7729x over previous
//
#include <hip/hip_runtime.h>
#include <math.h>

typedef float f32x16 __attribute__((ext_vector_type(16)));
typedef __bf16 bf16x8 __attribute__((ext_vector_type(8)));

constexpr int DEG = 64;
constexpr int KC  = 32;
constexpr int D   = 64;
constexpr float EPS = 1.1920929e-05f;  // 100 * f32 eps

// LDS layout (hi only): row-major [64 rows][8 chunks of 16B], chunk c of row r
// at slot (c ^ (r&7)) -> ushort idx = row*64 + slot*8. Staged via
// global_load_lds with pre-permuted SOURCE chunk sc=(l&7)^(l>>3), linear dest.
__device__ __forceinline__ int yidx(int row, int c) {
    return (row << 6) + (((c ^ (row & 7)) & 7) << 3);
}

// ---------------- prep: x(f32) -> xhi/xlo(bf16, row-major) + row norms ----------------
__global__ __launch_bounds__(256)
void rgc_prep(const float* __restrict__ x,
              unsigned short* __restrict__ xhi,
              unsigned short* __restrict__ xlo,
              float* __restrict__ xnrm, int nrows) {
    const int id  = blockIdx.x * 256 + threadIdx.x;
    const int row = id >> 3;
    const int c   = id & 7;
    if (row >= nrows) return;
    const float* src = x + ((size_t)row << 6) + (c << 3);
    const float4 v0 = *reinterpret_cast<const float4*>(src);
    const float4 v1 = *reinterpret_cast<const float4*>(src + 4);
    const float fv[8] = {v0.x, v0.y, v0.z, v0.w, v1.x, v1.y, v1.z, v1.w};
    bf16x8 h, e;
    float s = 0.f;
    #pragma unroll
    for (int j = 0; j < 8; ++j) {
        const float f = fv[j];
        s += f * f;
        const __bf16 hb = (__bf16)f;   // RNE
        h[j] = hb;
        e[j] = (__bf16)(f - (float)hb);
    }
    s += __shfl_xor(s, 1); s += __shfl_xor(s, 2); s += __shfl_xor(s, 4);
    if (c == 0) xnrm[row] = s;
    const size_t o = ((size_t)row << 6) + (c << 3);
    *reinterpret_cast<bf16x8*>(xhi + o) = h;
    *reinterpret_cast<bf16x8*>(xlo + o) = e;
}

// ------- main: 2 independent waves/block (2 nodes), 8 KB LDS each, no barriers -------
__global__ __launch_bounds__(128, 4)
void rgc_main(const unsigned short* __restrict__ xhi,
              const unsigned short* __restrict__ xlo,
              const float* __restrict__ xnrm,
              const int*   __restrict__ nbr,
              float*       __restrict__ out) {
    __shared__ __align__(16) unsigned short yh[2][4096];  // 8 KB per wave

    const int t  = threadIdx.x;
    const int wv = t >> 6;
    const int l  = t & 63;
    const long node = (long)blockIdx.x * 2 + wv;

    const int   my = nbr[node * 64 + l];
    const float nr = xnrm[my];          // lane l = norm of neighbor-row l

    const int frow = l & 31;
    const int kh   = l >> 5;

    // ---- lo fragments: direct per-lane gathers (issued early, overlap staging) ----
    const int gb = __shfl(my, frow);          // B rows 0..31
    const int ga = __shfl(my, 32 + frow);     // A rows 32..63
    bf16x8 blx[4], alx[4];
    #pragma unroll
    for (int s = 0; s < 4; ++s) {
        blx[s] = *reinterpret_cast<const bf16x8*>(xlo + ((size_t)gb << 6) + ((2 * s + kh) << 3));
        alx[s] = *reinterpret_cast<const bf16x8*>(xlo + ((size_t)ga << 6) + ((2 * s + kh) << 3));
    }

    // ---- hi staging: instr j covers rows 8j..8j+7 fully (16 lines/instr) ----
    unsigned short* yb = &yh[wv][0];
    const int sc = (l & 7) ^ (l >> 3);   // source chunk -> lands at slot l&7
    #pragma unroll
    for (int j = 0; j < 8; ++j) {
        const int g = __shfl(my, 8 * j + (l >> 3));
        const size_t so = ((size_t)g << 6) + (sc << 3);
        __builtin_amdgcn_global_load_lds(
            (const __attribute__((address_space(1))) unsigned int*)(xhi + so),
            (__attribute__((address_space(3))) unsigned int*)(yb + (j << 9)),
            16, 0, 0);
    }
    asm volatile("s_waitcnt vmcnt(0)" ::: "memory");
    __builtin_amdgcn_sched_barrier(0);
    // waves are independent: no s_barrier anywhere

    // ---- hi fragments from LDS ----
    bf16x8 bh[4], ah2[4];
    #pragma unroll
    for (int s = 0; s < 4; ++s) {
        const int c = 2 * s + kh;
        bh[s]  = *reinterpret_cast<const bf16x8*>(&yb[yidx(frow, c)]);
        ah2[s] = *reinterpret_cast<const bf16x8*>(&yb[yidx(32 + frow, c)]);
    }

    // ---- Gram: D = Xm · Xk^T; k = lane dim (l&31), m = reg dim ----
    f32x16 acc0 = {}, acc1 = {};
    #pragma unroll
    for (int s = 0; s < 4; ++s) {
        acc0 = __builtin_amdgcn_mfma_f32_32x32x16_bf16(bh[s],  bh[s],  acc0, 0, 0, 0);
        acc1 = __builtin_amdgcn_mfma_f32_32x32x16_bf16(ah2[s], bh[s],  acc1, 0, 0, 0);
    }
    #pragma unroll
    for (int s = 0; s < 4; ++s) {
        acc0 = __builtin_amdgcn_mfma_f32_32x32x16_bf16(bh[s],  blx[s], acc0, 0, 0, 0);
        acc1 = __builtin_amdgcn_mfma_f32_32x32x16_bf16(ah2[s], blx[s], acc1, 0, 0, 0);
    }
    #pragma unroll
    for (int s = 0; s < 4; ++s) {
        acc0 = __builtin_amdgcn_mfma_f32_32x32x16_bf16(blx[s], bh[s],  acc0, 0, 0, 0);
        acc1 = __builtin_amdgcn_mfma_f32_32x32x16_bf16(alx[s], bh[s],  acc1, 0, 0, 0);
    }

    // ---- sq -> l2 -> dist (reduce over all 64 m in-register + 1 shfl) ----
    const float nk = __shfl(nr, frow);
    float s = 0.f;
    #pragma unroll
    for (int r = 0; r < 16; ++r) {
        const int   m  = (r & 3) + 8 * (r >> 2) + 4 * kh;
        const float nm = __shfl(nr, m);
        const float sq = __builtin_fmaf(-2.0f, acc0[r], nm + nk);
        s += __builtin_amdgcn_sqrtf(__builtin_fabsf(sq) + EPS);
    }
    #pragma unroll
    for (int r = 0; r < 16; ++r) {
        const int   m  = 32 + (r & 3) + 8 * (r >> 2) + 4 * kh;
        const float nm = __shfl(nr, m);
        const float sq = __builtin_fmaf(-2.0f, acc1[r], nm + nk);
        s += __builtin_amdgcn_sqrtf(__builtin_fabsf(sq) + EPS);
    }
    s += __shfl_xor(s, 32);   // full dist_k at lanes k and k+32

    // ---- softmax over 32 candidates (in-wave, replicated across halves) ----
    float dmin = s;
    #pragma unroll
    for (int m = 1; m <= 16; m <<= 1) dmin = fminf(dmin, __shfl_xor(dmin, m));
    const float ez = __expf(dmin - s);
    float Z = ez;
    #pragma unroll
    for (int m = 1; m <= 16; m <<= 1) Z += __shfl_xor(Z, m);
    const float ezs = ez * (64.0f / Z);   // lane k holds w_k (row_sum = DEG)

    // ---- output (hi-only reconstruction): lane l -> d-pair (2*(l&31), +1) ----
    const int d0 = (l & 31) << 1;
    float oe = 0.f, oo = 0.f;
    #pragma unroll
    for (int kk = 0; kk < 16; ++kk) {
        const int k  = (kh << 4) + kk;
        const float wk = __shfl(ezs, k);
        const int idx = (k << 6) + ((((d0 >> 3) ^ (k & 7)) & 7) << 3) + (d0 & 7);
        const unsigned uh = *reinterpret_cast<const unsigned*>(&yb[idx]);
        oe = __builtin_fmaf(wk, __uint_as_float(uh << 16), oe);
        oo = __builtin_fmaf(wk, __uint_as_float(uh & 0xffff0000u), oo);
    }
    oe += __shfl_xor(oe, 32);
    oo += __shfl_xor(oo, 32);
    if (l < 32) {
        float2 v = make_float2(oe, oo);
        *reinterpret_cast<float2*>(out + ((size_t)node << 6) + (l << 1)) = v;
    }
}

// ---------------- fallback (no workspace): R4 path ----------------
__device__ __forceinline__ int yidx_cm(int row, int chunk) {  // old chunk-major
    return (chunk << 9) + ((row ^ chunk) << 3);
}

__global__ __launch_bounds__(128, 4)
void rgc_fallback(const float* __restrict__ x,
                  const int*   __restrict__ nbr,
                  float*       __restrict__ out) {
    __shared__ __align__(16) unsigned short yhi[4096];
    __shared__ __align__(16) unsigned short ylo[4096];
    __shared__ float nrm[64];
    __shared__ float wsh[KC];
    __shared__ float pdist[64];
    __shared__ float obuf[64];

    const int n = blockIdx.x;
    const int t = threadIdx.x;
    const int w = t >> 6;
    const int l = t & 63;

    const int srow = t >> 3;
    const int sc   = t & 7;
    int gidx[4];
    #pragma unroll
    for (int it = 0; it < 4; ++it)
        gidx[it] = nbr[(n << 6) + it * 16 + srow];

    #pragma unroll
    for (int it = 0; it < 4; ++it) {
        const int row = it * 16 + srow;
        const float* src = x + ((size_t)gidx[it] << 6) + (sc << 3);
        const float4 v0 = *reinterpret_cast<const float4*>(src);
        const float4 v1 = *reinterpret_cast<const float4*>(src + 4);
        const float fv[8] = {v0.x, v0.y, v0.z, v0.w, v1.x, v1.y, v1.z, v1.w};
        float s = 0.f;
        bf16x8 h, e;
        #pragma unroll
        for (int j = 0; j < 8; ++j) {
            const float f = fv[j];
            s += f * f;
            const __bf16 hb = (__bf16)f;
            h[j] = hb;
            e[j] = (__bf16)(f - (float)hb);
        }
        s += __shfl_xor(s, 1); s += __shfl_xor(s, 2); s += __shfl_xor(s, 4);
        if (sc == 0) nrm[row] = s;
        const int base = yidx_cm(row, sc);
        *reinterpret_cast<bf16x8*>(&yhi[base]) = h;
        *reinterpret_cast<bf16x8*>(&ylo[base]) = e;
    }
    __syncthreads();

    const int frow = l & 31;
    const int kh   = l >> 5;
    bf16x8 amh[4], aml[4], bkh[4], bkl[4];
    #pragma unroll
    for (int s = 0; s < 4; ++s) {
        const int c  = 2 * s + kh;
        const int kb = yidx_cm(frow, c);
        bkh[s] = *reinterpret_cast<bf16x8*>(&yhi[kb]);
        bkl[s] = *reinterpret_cast<bf16x8*>(&ylo[kb]);
    }
    if (w == 0) {
        #pragma unroll
        for (int s = 0; s < 4; ++s) { amh[s] = bkh[s]; aml[s] = bkl[s]; }
    } else {
        #pragma unroll
        for (int s = 0; s < 4; ++s) {
            const int c  = 2 * s + kh;
            const int mb = yidx_cm(32 + frow, c);
            amh[s] = *reinterpret_cast<bf16x8*>(&yhi[mb]);
            aml[s] = *reinterpret_cast<bf16x8*>(&ylo[mb]);
        }
    }

    f32x16 acc = {};
    #pragma unroll
    for (int s = 0; s < 4; ++s)
        acc = __builtin_amdgcn_mfma_f32_32x32x16_bf16(amh[s], bkh[s], acc, 0, 0, 0);
    #pragma unroll
    for (int s = 0; s < 4; ++s)
        acc = __builtin_amdgcn_mfma_f32_32x32x16_bf16(amh[s], bkl[s], acc, 0, 0, 0);
    #pragma unroll
    for (int s = 0; s < 4; ++s)
        acc = __builtin_amdgcn_mfma_f32_32x32x16_bf16(aml[s], bkh[s], acc, 0, 0, 0);

    const float nk  = nrm[frow];
    const int   mb0 = w * 32 + 4 * kh;
    float s = 0.f;
    #pragma unroll
    for (int r = 0; r < 16; ++r) {
        const float nm = nrm[mb0 + (r & 3) + 8 * (r >> 2)];
        const float sq = __builtin_fmaf(-2.0f, acc[r], nm + nk);
        s += __builtin_amdgcn_sqrtf(__builtin_fabsf(sq) + EPS);
    }
    s += __shfl_xor(s, 32);
    if (l < 32) pdist[w * 32 + l] = s;
    __syncthreads();

    const float dsum = pdist[frow] + pdist[32 + frow];
    float dmin = dsum;
    #pragma unroll
    for (int m = 1; m <= 16; m <<= 1) dmin = fminf(dmin, __shfl_xor(dmin, m));
    const float ez = __expf(dmin - dsum);
    float Z = ez;
    #pragma unroll
    for (int m = 1; m <= 16; m <<= 1) Z += __shfl_xor(Z, m);
    if (t < 32) wsh[frow] = ez * (64.0f / Z);
    __syncthreads();

    const int oc = l >> 3;
    const int ow = l & 7;
    float o = 0.f;
    #pragma unroll
    for (int kk = 0; kk < 16; ++kk) {
        const int kx = w * 16 + kk;
        const int bi = yidx_cm(kx, oc) + ow;
        const float f = __uint_as_float((unsigned)yhi[bi] << 16)
                      + __uint_as_float((unsigned)ylo[bi] << 16);
        o += wsh[kx] * f;
    }
    if (w == 1) obuf[l] = o;
    __syncthreads();
    if (w == 0) out[(size_t)n * D + l] = o + obuf[l];
}

extern "C" void kernel_launch(void* const* d_in, const int* in_sizes, int n_in,
                              void* d_out, int out_size, void* d_ws, size_t ws_size,
                              hipStream_t stream) {
    const float* x   = (const float*)d_in[0];
    const int*   nbr = (const int*)d_in[1];
    float*       out = (float*)d_out;
    const int n_nodes = in_sizes[0] / D;   // 20000
    const size_t need = (size_t)n_nodes * D * 2 * sizeof(unsigned short)
                      + (size_t)n_nodes * sizeof(float);
    if (d_ws != nullptr && ws_size >= need && (n_nodes % 2) == 0) {
        unsigned short* xhi  = (unsigned short*)d_ws;
        unsigned short* xlo  = xhi + (size_t)n_nodes * D;
        float*          xnrm = (float*)(xlo + (size_t)n_nodes * D);
        const int tasks = n_nodes * 8;
        rgc_prep<<<(tasks + 255) / 256, 256, 0, stream>>>(x, xhi, xlo, xnrm, n_nodes);
        rgc_main<<<n_nodes / 2, 128, 0, stream>>>(xhi, xlo, xnrm, nbr, out);
    } else {
        rgc_fallback<<<n_nodes, 128, 0, stream>>>(x, nbr, out);
    }
}